// Round 2
// baseline (128.999 us; speedup 1.0000x reference)
//
#include <hip/hip_runtime.h>
#include <cstdint>

// BasisFunction1D: out[o,b] = sum_i (1-d)*P[idx,o,i] + d*P[idx+1,o,i]
//   idx,d from Laplace-CDF bucketization of x[i,b] on a 128-chunk grid.
//
// R1 strategy (XCD-pinned L2-resident gathers):
//   K1 build_q: Q[i][g][o] = pack_f16x2( P[g,o,i], P[g+1,o,i]-P[g,o,i] )  (8.4 MB)
//   K2 build_t: T[i][b]    = pack{ u16 idx | f16 d << 16 }  (elementwise, x layout)
//   K3 main:    output o-dim split into 8 slices of 16 o's; slice s is handled
//               only by blocks with blockIdx%8 == s, which land on XCD s
//               (round-robin dispatch) -> per-XCD Q working set = 1.05 MB,
//               L2-resident. Wave = 8 lane-groups of 8; group g owns batch b,
//               lane owns 2 o's; one global_load_dwordx2 = 512 B, 8 b's/iter.

#define NG 128   // grids
#define NI 128   // input dim
#define NO 128   // output dim
#define NB 8192  // batch

using half2v = __attribute__((ext_vector_type(2))) _Float16;

__device__ inline uint32_t pack_f16x2(float lo, float hi) {
    _Float16 hl = (_Float16)lo, hh = (_Float16)hi;
    return (uint32_t)__builtin_bit_cast(unsigned short, hl) |
           ((uint32_t)__builtin_bit_cast(unsigned short, hh) << 16);
}

// ---- K1: transpose+delta-pack func_parameter -> Q[i][g][o] (f16x2) ----
__global__ __launch_bounds__(256) void build_q(const float* __restrict__ P,
                                               uint32_t* __restrict__ Q) {
    __shared__ float lp[32][129];
    __shared__ float ln[32][129];
    const int g  = blockIdx.x >> 2;
    const int o0 = (blockIdx.x & 3) * 32;
    const int t  = threadIdx.x;
    #pragma unroll
    for (int p = 0; p < 16; ++p) {
        int e = p * 256 + t;
        int ol = e >> 7, i = e & 127;
        lp[ol][i] = P[(size_t)(g * NO + o0 + ol) * NI + i];
        ln[ol][i] = P[(size_t)((g + 1) * NO + o0 + ol) * NI + i];
    }
    __syncthreads();
    #pragma unroll
    for (int p = 0; p < 16; ++p) {
        int e = p * 256 + t;
        int i = e >> 5, ol = e & 31;
        float pl = lp[ol][i];
        float dd = ln[ol][i] - pl;
        Q[((size_t)i * NG + g) * NO + o0 + ol] = pack_f16x2(pl, dd);
    }
}

// ---- K2: bucketize x -> T[i][b] = {u16 idx | f16 d << 16}; same layout as x ----
__global__ __launch_bounds__(256) void build_t(const float* __restrict__ x,
                                               const float* __restrict__ borders,
                                               const float* __restrict__ icl,
                                               uint32_t* __restrict__ T) {
    const int e0 = (blockIdx.x * 256 + threadIdx.x) * 4;
    const float4 xv = *(const float4*)(x + e0);
    uint32_t r[4];
    const float xs[4] = {xv.x, xv.y, xv.z, xv.w};
    #pragma unroll
    for (int k = 0; k < 4; ++k) {
        float v = xs[k];
        float ea = __expf(-fabsf(v));
        float cdf = v > 0.f ? 1.f - 0.5f * ea : 0.5f * ea;
        int idx = (int)(cdf * 128.f);
        idx = idx > 127 ? 127 : idx;
        float d = (v - borders[idx]) * icl[idx];
        _Float16 hd = (_Float16)d;
        r[k] = (uint32_t)idx |
               ((uint32_t)__builtin_bit_cast(unsigned short, hd) << 16);
    }
    *(uint4*)(T + e0) = make_uint4(r[0], r[1], r[2], r[3]);
}

// ---- K3: main gather-dot. 8 o-slices pinned to XCDs; 32 b + 16 o per block ----
__global__ __launch_bounds__(256) void main_k(const uint32_t* __restrict__ Q,
                                              const uint32_t* __restrict__ T,
                                              float* __restrict__ out) {
    __shared__ float sout[32][17];
    const int t     = threadIdx.x;
    const int wv    = t >> 6;
    const int lane  = t & 63;
    const int slice = blockIdx.x & 7;          // == XCD id under round-robin
    const int jb    = blockIdx.x >> 3;
    const int bblk  = jb * 32;                 // 32 batches per block
    const int o0    = slice * 16;              // 16 outputs per slice
    const int grp   = lane >> 3;               // 8 lane-groups -> 8 b's per wave
    const int bme   = bblk + wv * 8 + grp;     // this lane's batch
    const uint32_t lane_const = (uint32_t)(o0 * 4 + (lane & 7) * 8);

    const char* Qb = (const char*)Q;
    float acc0 = 0.f, acc1 = 0.f;
    #pragma unroll 8
    for (int i = 0; i < NI; ++i) {
        uint32_t tw  = T[(size_t)i * NB + bme];
        uint32_t idx = tw & 0xFFFFu;
        uint32_t wb  = (tw & 0xFFFF0000u) | 0x3C00u;   // {lo=1.0h, hi=d_h}
        uint2 q = *(const uint2*)(Qb + ((size_t)i << 16) + (idx << 9) + lane_const);
        half2v w2 = __builtin_bit_cast(half2v, wb);
        acc0 = __builtin_amdgcn_fdot2(__builtin_bit_cast(half2v, q.x), w2, acc0, false);
        acc1 = __builtin_amdgcn_fdot2(__builtin_bit_cast(half2v, q.y), w2, acc1, false);
    }
    const int oc = (lane & 7) * 2;
    sout[wv * 8 + grp][oc]     = acc0;
    sout[wv * 8 + grp][oc + 1] = acc1;
    __syncthreads();
    // store: per o, 32 consecutive b -> 128 B contiguous runs, nontemporal
    #pragma unroll
    for (int p = 0; p < 2; ++p) {
        int e = p * 256 + t;
        int ol = e >> 5, bl = e & 31;
        __builtin_nontemporal_store(sout[bl][ol],
                                    &out[(size_t)(o0 + ol) * NB + bblk + bl]);
    }
}

extern "C" void kernel_launch(void* const* d_in, const int* in_sizes, int n_in,
                              void* d_out, int out_size, void* d_ws, size_t ws_size,
                              hipStream_t stream) {
    const float* x       = (const float*)d_in[0];
    const float* P       = (const float*)d_in[1];
    const float* borders = (const float*)d_in[2];
    const float* icl     = (const float*)d_in[3];
    float* out = (float*)d_out;

    uint32_t* Q = (uint32_t*)d_ws;                       // 128*128*128 u32 = 8.4 MB
    uint32_t* T = Q + (size_t)NI * NG * NO;              // 128*8192  u32 = 4.2 MB

    hipLaunchKernelGGL(build_q, dim3(NG * 4), dim3(256), 0, stream, P, Q);
    hipLaunchKernelGGL(build_t, dim3(NI * NB / 1024), dim3(256), 0, stream,
                       x, borders, icl, T);
    hipLaunchKernelGGL(main_k, dim3(NB / 4), dim3(256), 0, stream, Q, T, out);
}

// Round 3
// 100.675 us; speedup vs baseline: 1.2813x; 1.2813x over previous
//
#include <hip/hip_runtime.h>
#include <cstdint>

// BasisFunction1D: out[o,b] = sum_i (1-d)*P[idx,o,i] + d*P[idx+1,o,i]
//   idx,d from Laplace-CDF bucketization of x[i,b] on a 128-chunk grid.
//
// R2 strategy (request-rate bound -> widest fully-contiguous gathers):
//   K1 build_q: Q[i][g][o] = pack_f16x2( P[g,o,i], P[g+1,o,i]-P[g,o,i] )  (8.4 MB)
//   K2 build_t: T[i][b]    = pack{ u16 idx | f16 d << 16 }  (elementwise, x layout)
//   K3 main:    wave owns 2 batches (b0=lanes 0-31, b1=lanes 32-63); per i one
//               global_load_dwordx4 covers both 512-B Q rows (2 contiguous runs,
//               16 lines, 1024 useful bytes). T via s_load_dwordx2 (scalar pipe,
//               one s-cache line per i per block). 4 fdot2/lane/iter.
//               Epilogue: LDS transpose -> 64-B-aligned float4 stores.

#define NG 128   // grids
#define NI 128   // input dim
#define NO 128   // output dim
#define NB 8192  // batch

using half2v = __attribute__((ext_vector_type(2))) _Float16;

__device__ inline uint32_t pack_f16x2(float lo, float hi) {
    _Float16 hl = (_Float16)lo, hh = (_Float16)hi;
    return (uint32_t)__builtin_bit_cast(unsigned short, hl) |
           ((uint32_t)__builtin_bit_cast(unsigned short, hh) << 16);
}

// ---- K1: transpose+delta-pack func_parameter -> Q[i][g][o] (f16x2) ----
__global__ __launch_bounds__(256) void build_q(const float* __restrict__ P,
                                               uint32_t* __restrict__ Q) {
    __shared__ float lp[32][129];
    __shared__ float ln[32][129];
    const int g  = blockIdx.x >> 2;
    const int o0 = (blockIdx.x & 3) * 32;
    const int t  = threadIdx.x;
    #pragma unroll
    for (int p = 0; p < 16; ++p) {
        int e = p * 256 + t;
        int ol = e >> 7, i = e & 127;
        lp[ol][i] = P[(size_t)(g * NO + o0 + ol) * NI + i];
        ln[ol][i] = P[(size_t)((g + 1) * NO + o0 + ol) * NI + i];
    }
    __syncthreads();
    #pragma unroll
    for (int p = 0; p < 16; ++p) {
        int e = p * 256 + t;
        int i = e >> 5, ol = e & 31;
        float pl = lp[ol][i];
        float dd = ln[ol][i] - pl;
        Q[((size_t)i * NG + g) * NO + o0 + ol] = pack_f16x2(pl, dd);
    }
}

// ---- K2: bucketize x -> T[i][b] = {u16 idx | f16 d << 16}; same layout as x ----
__global__ __launch_bounds__(256) void build_t(const float* __restrict__ x,
                                               const float* __restrict__ borders,
                                               const float* __restrict__ icl,
                                               uint32_t* __restrict__ T) {
    const int e0 = (blockIdx.x * 256 + threadIdx.x) * 4;
    const float4 xv = *(const float4*)(x + e0);
    uint32_t r[4];
    const float xs[4] = {xv.x, xv.y, xv.z, xv.w};
    #pragma unroll
    for (int k = 0; k < 4; ++k) {
        float v = xs[k];
        float ea = __expf(-fabsf(v));
        float cdf = v > 0.f ? 1.f - 0.5f * ea : 0.5f * ea;
        int idx = (int)(cdf * 128.f);
        idx = idx > 127 ? 127 : idx;
        float d = (v - borders[idx]) * icl[idx];
        _Float16 hd = (_Float16)d;
        r[k] = (uint32_t)idx |
               ((uint32_t)__builtin_bit_cast(unsigned short, hd) << 16);
    }
    *(uint4*)(T + e0) = make_uint4(r[0], r[1], r[2], r[3]);
}

// ---- K3: main gather-dot. 512 thr, 8 waves, 2 b/wave, 4 o/lane, dwordx4 ----
__global__ __launch_bounds__(512) void main_k(const uint32_t* __restrict__ Q,
                                              const uint32_t* __restrict__ T,
                                              float* __restrict__ out) {
    __shared__ float sout[16][132];
    const int t    = threadIdx.x;
    const int wv   = t >> 6;
    const int lane = t & 63;
    const int bblk = blockIdx.x * 16;
    const int b0   = __builtin_amdgcn_readfirstlane(bblk + wv * 2); // SGPR
    const bool hi  = lane >= 32;
    const uint32_t laneoff = (uint32_t)((lane & 31) * 16);

    const char* Qb = (const char*)Q;
    float a0 = 0.f, a1 = 0.f, a2 = 0.f, a3 = 0.f;
    #pragma unroll 8
    for (int i = 0; i < NI; ++i) {
        // scalar pipe: both b's T words in one s_load_dwordx2
        uint64_t tt = *(const uint64_t*)(T + (size_t)i * NB + b0);
        uint32_t t0 = (uint32_t)tt;
        uint32_t t1 = (uint32_t)(tt >> 32);
        uint32_t w0 = (t0 & 0xFFFF0000u) | 0x3C00u;    // {lo=1.0h, hi=d0}
        uint32_t w1 = (t1 & 0xFFFF0000u) | 0x3C00u;
        uint32_t q0 = (t0 & 127u) << 9;                // idx0 * 512 B
        uint32_t q1 = (t1 & 127u) << 9;
        uint32_t wb  = hi ? w1 : w0;                   // v_cndmask
        uint32_t off = (uint32_t)(i << 16) + (hi ? q1 : q0) + laneoff;
        uint4 q = *(const uint4*)(Qb + off);           // dwordx4, 2x512B runs
        half2v w2 = __builtin_bit_cast(half2v, wb);
        a0 = __builtin_amdgcn_fdot2(__builtin_bit_cast(half2v, q.x), w2, a0, false);
        a1 = __builtin_amdgcn_fdot2(__builtin_bit_cast(half2v, q.y), w2, a1, false);
        a2 = __builtin_amdgcn_fdot2(__builtin_bit_cast(half2v, q.z), w2, a2, false);
        a3 = __builtin_amdgcn_fdot2(__builtin_bit_cast(half2v, q.w), w2, a3, false);
    }
    // lane -> sout[b_local][o..o+3]
    {
        int r = wv * 2 + (hi ? 1 : 0);
        int c = (lane & 31) * 4;
        *(float4*)&sout[r][c] = make_float4(a0, a1, a2, a3);
    }
    __syncthreads();
    // cooperative store: thread -> one float4 along b; 4 threads = 64-B line
    {
        int o  = t >> 2;
        int bq = t & 3;
        float4 v = make_float4(sout[bq * 4 + 0][o], sout[bq * 4 + 1][o],
                               sout[bq * 4 + 2][o], sout[bq * 4 + 3][o]);
        __builtin_nontemporal_store(v.x, &out[(size_t)o * NB + bblk + bq * 4 + 0]);
        __builtin_nontemporal_store(v.y, &out[(size_t)o * NB + bblk + bq * 4 + 1]);
        __builtin_nontemporal_store(v.z, &out[(size_t)o * NB + bblk + bq * 4 + 2]);
        __builtin_nontemporal_store(v.w, &out[(size_t)o * NB + bblk + bq * 4 + 3]);
    }
}

extern "C" void kernel_launch(void* const* d_in, const int* in_sizes, int n_in,
                              void* d_out, int out_size, void* d_ws, size_t ws_size,
                              hipStream_t stream) {
    const float* x       = (const float*)d_in[0];
    const float* P       = (const float*)d_in[1];
    const float* borders = (const float*)d_in[2];
    const float* icl     = (const float*)d_in[3];
    float* out = (float*)d_out;

    uint32_t* Q = (uint32_t*)d_ws;                       // 128*128*128 u32 = 8.4 MB
    uint32_t* T = Q + (size_t)NI * NG * NO;              // 128*8192  u32 = 4.2 MB

    hipLaunchKernelGGL(build_q, dim3(NG * 4), dim3(256), 0, stream, P, Q);
    hipLaunchKernelGGL(build_t, dim3(NI * NB / 1024), dim3(256), 0, stream,
                       x, borders, icl, T);
    hipLaunchKernelGGL(main_k, dim3(NB / 16), dim3(512), 0, stream, Q, T, out);
}